// Round 2
// baseline (1672.381 us; speedup 1.0000x reference)
//
#include <hip/hip_runtime.h>

// FlowTransformerBlock on gfx950. B=2, T=2, C=128, H=W=256, PS=8, N_HEAD=1.
// ALL global I/O is FP32 (reference dtypes). Internal matmuls are bf16 MFMA.
//
// ws layout (exactly 256 MiB):
//   Qn   fp32 NHWC  2 imgs  [0,          67108864)   (attn writes Qon in-place)
//   KVn  bf16 NHWC  4 imgs  [67108864,  134217728)
//   KVwn bf16 NHWC  8 imgs  [134217728, 268435456)
// Weights (bf16, [s][o][ci], 294912 B each):
//   wtq  -> d_out bytes [0, 294912)        (d_out is dead until final conv)
//   wtkv -> d_out bytes [294912, 589824)
//   wtff -> KVwn head, prepped AFTER attn (KVwn dead by then)

typedef unsigned short u16;
typedef __attribute__((ext_vector_type(8))) __bf16 bf16x8;
typedef __attribute__((ext_vector_type(4))) float f32x4;

union F4 { float4 v; float f[4]; };
union US4 { ushort4 s; u16 u[4]; };
union V16 { int4 i4; ushort4 s4[2]; u16 u[8]; };

__device__ __forceinline__ u16 f2b(float f) {
  union { float f; unsigned u; } c; c.f = f;
  unsigned r = c.u + 0x7fffu + ((c.u >> 16) & 1u);
  return (u16)(r >> 16);
}
__device__ __forceinline__ bf16x8 ld8(const u16* p) {
  union { ushort4 s[2]; bf16x8 v; } u;
  u.s[0] = *(const ushort4*)p;
  u.s[1] = *(const ushort4*)(p + 4);
  return u.v;
}

#define HW 65536

// ---- weight reorder: Wt[s][o][ci] (bf16) = W[o][ci][ky][kx] (fp32) --------
__global__ void prep_w(const float* __restrict__ W, u16* __restrict__ Wt) {
  int i = blockIdx.x * 256 + threadIdx.x;
  if (i >= 9 * 128 * 128) return;
  int s = i / 16384, rem = i % 16384;
  int o = rem >> 7, ci = rem & 127;
  Wt[i] = f2b(W[(o * 128 + ci) * 9 + s]);
}

// ---- conv 3x3 + bias + prelu + residual -----------------------------------
// One WG: 128 out-ch x 64 px (row y, x0..x0+63). MFMA 16x16x32 bf16.
// x_nhwc: input layout. out_mode: 0=NCHW f32, 1=NHWC f32, 2=NHWC bf16.
__global__ __launch_bounds__(256, 2) void conv3x3_k(
    const float* __restrict__ X, const u16* __restrict__ Wt,
    const float* __restrict__ bias, const float* __restrict__ alpha,
    void* __restrict__ Out, int x_nhwc, int out_mode) {
  __shared__ __align__(16) char smem[44352];
  u16* in_t = (u16*)smem;            // [r][ix 0..65][ci_half], stride 68, 26928 B
  u16* w_t = (u16*)(smem + 26928);   // [o][ci_half], stride 68, 17408 B
  float* o_t = (float*)smem;         // epilogue alias (mode 1): [px][132] f32
  u16* ob_t = (u16*)smem;            // epilogue alias (mode 2): [px][132] u16

  const int blk = blockIdx.x;
  const int xb = blk & 3, y = (blk >> 2) & 255, img = blk >> 10;
  const int x0 = xb * 64;
  const int tid = threadIdx.x;
  const int lane = tid & 63, wv = tid >> 6;
  const int quad = lane >> 4, l15 = lane & 15;

  f32x4 acc[2][4];
  const f32x4 zero4 = {0.f, 0.f, 0.f, 0.f};
#pragma unroll
  for (int i = 0; i < 2; ++i)
#pragma unroll
    for (int j = 0; j < 4; ++j) acc[i][j] = zero4;

  const float alf = alpha[0];

  for (int h = 0; h < 2; ++h) {
    __syncthreads();
    if (x_nhwc) {
      // 3r * 66ix * 16 float4-chunks of the 64-ch half
      for (int i = tid; i < 3168; i += 256) {
        int r = i / 1056, rem = i % 1056, ix = rem >> 4, c4 = rem & 15;
        int yy = y - 1 + r, xx = x0 - 1 + ix;
        F4 v;
        if ((unsigned)yy < 256u && (unsigned)xx < 256u)
          v.v = *(const float4*)(X + (((img * 256 + yy) * 256 + xx) * 128 + h * 64 + c4 * 4));
        else
          v.v = (float4){0.f, 0.f, 0.f, 0.f};
        US4 s;
#pragma unroll
        for (int j = 0; j < 4; ++j) s.u[j] = f2b(v.f[j]);
        *(ushort4*)&in_t[(r * 66 + ix) * 68 + c4 * 4] = s.s;
      }
    } else {
      // interior: 64c * 3r * 16 float4-chunks (4 px each)
      for (int i = tid; i < 3072; i += 256) {
        int c = i / 48, rem = i % 48, r = rem >> 4, c4 = rem & 15;
        int yy = y - 1 + r;
        F4 v;
        if ((unsigned)yy < 256u)
          v.v = *(const float4*)(X + ((img * 128 + h * 64 + c) * HW + yy * 256 + x0 + c4 * 4));
        else
          v.v = (float4){0.f, 0.f, 0.f, 0.f};
        int li = (r * 66 + 1 + c4 * 4) * 68 + c;
#pragma unroll
        for (int j = 0; j < 4; ++j) in_t[li + j * 68] = f2b(v.f[j]);
      }
      for (int i = tid; i < 384; i += 256) {  // edge columns ix=0,65
        int c = i / 6, rem = i % 6, r = rem >> 1, e = rem & 1;
        int yy = y - 1 + r;
        int xx = e ? (x0 + 64) : (x0 - 1);
        u16 val = 0;
        if ((unsigned)yy < 256u && (unsigned)xx < 256u)
          val = f2b(X[(img * 128 + h * 64 + c) * HW + yy * 256 + xx]);
        in_t[(r * 66 + (e ? 65 : 0)) * 68 + c] = val;
      }
    }
    __syncthreads();
    for (int s = 0; s < 9; ++s) {
      const int ky = s / 3, kx = s % 3;
      if (s) __syncthreads();
      for (int i = tid; i < 1024; i += 256) {  // stage W slice half
        int o = i >> 3, ch = i & 7;
        V16 v;
        v.i4 = *(const int4*)(Wt + (s * 16384 + o * 128 + h * 64 + ch * 8));
        int li = o * 68 + ch * 8;
        *(ushort4*)&w_t[li] = v.s4[0];
        *(ushort4*)&w_t[li + 4] = v.s4[1];
      }
      __syncthreads();
#pragma unroll
      for (int kb = 0; kb < 2; ++kb) {
        const int c0 = kb * 32 + quad * 8;
        bf16x8 a0 = ld8(&w_t[(wv * 32 + l15) * 68 + c0]);
        bf16x8 a1 = ld8(&w_t[(wv * 32 + 16 + l15) * 68 + c0]);
#pragma unroll
        for (int nt = 0; nt < 4; ++nt) {
          int ix = nt * 16 + l15 + kx;
          bf16x8 b = ld8(&in_t[(ky * 66 + ix) * 68 + c0]);
          acc[0][nt] = __builtin_amdgcn_mfma_f32_16x16x32_bf16(a0, b, acc[0][nt], 0, 0, 0);
          acc[1][nt] = __builtin_amdgcn_mfma_f32_16x16x32_bf16(a1, b, acc[1][nt], 0, 0, 0);
        }
      }
    }
  }
  // ---- epilogue (residual read from global fp32) ----
  __syncthreads();
  if (out_mode == 0) {
    float* Outf = (float*)Out;
#pragma unroll
    for (int mt = 0; mt < 2; ++mt)
#pragma unroll
      for (int nt = 0; nt < 4; ++nt)
#pragma unroll
        for (int r = 0; r < 4; ++r) {
          int ch = wv * 32 + mt * 16 + quad * 4 + r;
          int n = nt * 16 + l15;
          float xres = x_nhwc ? X[((img * 256 + y) * 256 + x0 + n) * 128 + ch]
                              : X[(img * 128 + ch) * HW + y * 256 + x0 + n];
          float v = acc[mt][nt][r] + bias[ch];
          v = v >= 0.f ? v : alf * v;
          Outf[(img * 128 + ch) * HW + y * 256 + x0 + n] = v + xres;
        }
  } else if (out_mode == 1) {
    float* Outf = (float*)Out;
#pragma unroll
    for (int mt = 0; mt < 2; ++mt)
#pragma unroll
      for (int nt = 0; nt < 4; ++nt)
#pragma unroll
        for (int r = 0; r < 4; ++r) {
          int ch = wv * 32 + mt * 16 + quad * 4 + r;
          int n = nt * 16 + l15;
          float xres = x_nhwc ? X[((img * 256 + y) * 256 + x0 + n) * 128 + ch]
                              : X[(img * 128 + ch) * HW + y * 256 + x0 + n];
          float v = acc[mt][nt][r] + bias[ch];
          v = v >= 0.f ? v : alf * v;
          o_t[n * 132 + ch] = v + xres;
        }
    __syncthreads();
    for (int i = tid; i < 2048; i += 256) {
      int px = i >> 5, c4 = i & 31;
      float4 v = *(const float4*)&o_t[px * 132 + c4 * 4];
      *(float4*)(Outf + (((img * 256 + y) * 256 + x0 + px) * 128 + c4 * 4)) = v;
    }
  } else {
    u16* Outb = (u16*)Out;
#pragma unroll
    for (int mt = 0; mt < 2; ++mt)
#pragma unroll
      for (int nt = 0; nt < 4; ++nt)
#pragma unroll
        for (int r = 0; r < 4; ++r) {
          int ch = wv * 32 + mt * 16 + quad * 4 + r;
          int n = nt * 16 + l15;
          float xres = x_nhwc ? X[((img * 256 + y) * 256 + x0 + n) * 128 + ch]
                              : X[(img * 128 + ch) * HW + y * 256 + x0 + n];
          float v = acc[mt][nt][r] + bias[ch];
          v = v >= 0.f ? v : alf * v;
          ob_t[n * 132 + ch] = f2b(v + xres);
        }
    __syncthreads();
    for (int i = tid; i < 1024; i += 256) {
      int px = i >> 4, c8 = i & 15;
      V16 v;
      v.s4[0] = *(const ushort4*)&ob_t[px * 132 + c8 * 8];
      v.s4[1] = *(const ushort4*)&ob_t[px * 132 + c8 * 8 + 4];
      *(int4*)(Outb + (((img * 256 + y) * 256 + x0 + px) * 128 + c8 * 8)) = v.i4;
    }
  }
}

// ---- windowed dual-branch attention ---------------------------------------
#define ATT_SCALE 0.08838834764831845f
#define LOG2E 1.4426950408889634f

template <int NB>  // NB = # of 64-key blocks (= T of the KV tensor)
__device__ __forceinline__ void attn_branch(
    const u16* __restrict__ kv, int b, int Y0, int X0,
    u16* kv_t, u16* p_t, const bf16x8 qf[4],
    int tid, int wv, int quad, int l15,
    f32x4 oacc[8], float lsum[4]) {
  f32x4 sacc[NB][4];
  const f32x4 zero4 = {0.f, 0.f, 0.f, 0.f};
#pragma unroll
  for (int i = 0; i < NB; ++i)
#pragma unroll
    for (int j = 0; j < 4; ++j) sacc[i][j] = zero4;

  // S = Q @ KV^T (K-dim = channels 128)
  for (int kb = 0; kb < NB; ++kb) {
    __syncthreads();
    for (int i = tid; i < 1024; i += 256) {   // [key][132] bf16
      int j = i >> 4, ch = i & 15;
      int yy = Y0 + (j >> 3), xx = X0 + (j & 7);
      int img = b * NB + kb;
      V16 v;
      v.i4 = *(const int4*)(kv + (((img * 256 + yy) * 256 + xx) * 128 + ch * 8));
      int li = j * 132 + ch * 8;
      *(ushort4*)&kv_t[li] = v.s4[0];
      *(ushort4*)&kv_t[li + 4] = v.s4[1];
    }
    __syncthreads();
#pragma unroll
    for (int kst = 0; kst < 4; ++kst) {
#pragma unroll
      for (int nt = 0; nt < 4; ++nt) {
        bf16x8 bk = ld8(&kv_t[(nt * 16 + l15) * 132 + kst * 32 + quad * 8]);
        sacc[kb][nt] = __builtin_amdgcn_mfma_f32_16x16x32_bf16(qf[kst], bk, sacc[kb][nt], 0, 0, 0);
      }
    }
  }
  // softmax (rows live across the 16 lanes of each quad)
  float mx[4];
#pragma unroll
  for (int r = 0; r < 4; ++r) {
    float m = -1e30f;
#pragma unroll
    for (int kb = 0; kb < NB; ++kb)
#pragma unroll
      for (int nt = 0; nt < 4; ++nt) m = fmaxf(m, sacc[kb][nt][r]);
    for (int d = 1; d < 16; d <<= 1) m = fmaxf(m, __shfl_xor(m, d, 64));
    mx[r] = m * ATT_SCALE;
  }
#pragma unroll
  for (int r = 0; r < 4; ++r) {
    float s = 0.f;
#pragma unroll
    for (int kb = 0; kb < NB; ++kb)
#pragma unroll
      for (int nt = 0; nt < 4; ++nt) {
        float p = exp2f((sacc[kb][nt][r] * ATT_SCALE - mx[r]) * LOG2E);
        sacc[kb][nt][r] = p;
        s += p;
      }
    for (int d = 1; d < 16; d <<= 1) s += __shfl_xor(s, d, 64);
    lsum[r] = s;
  }
  // O = P @ KV (K-dim = keys, 64/block)
#pragma unroll
  for (int i = 0; i < 8; ++i) oacc[i] = zero4;
  for (int kb = 0; kb < NB; ++kb) {
    __syncthreads();
    for (int i = tid; i < 1024; i += 256) {   // transposed KV: [d][68]
      int j = i >> 4, ch = i & 15;
      int yy = Y0 + (j >> 3), xx = X0 + (j & 7);
      int img = b * NB + kb;
      V16 v;
      v.i4 = *(const int4*)(kv + (((img * 256 + yy) * 256 + xx) * 128 + ch * 8));
#pragma unroll
      for (int cc = 0; cc < 8; ++cc) kv_t[(ch * 8 + cc) * 68 + j] = v.u[cc];
    }
#pragma unroll
    for (int nt = 0; nt < 4; ++nt)
#pragma unroll
      for (int r = 0; r < 4; ++r)
        p_t[(wv * 16 + quad * 4 + r) * 68 + nt * 16 + l15] = f2b(sacc[kb][nt][r]);
    __syncthreads();
#pragma unroll
    for (int kst = 0; kst < 2; ++kst) {
      bf16x8 ap = ld8(&p_t[(wv * 16 + l15) * 68 + kst * 32 + quad * 8]);
#pragma unroll
      for (int nt = 0; nt < 8; ++nt) {
        bf16x8 bv = ld8(&kv_t[(nt * 16 + l15) * 68 + kst * 32 + quad * 8]);
        oacc[nt] = __builtin_amdgcn_mfma_f32_16x16x32_bf16(ap, bv, oacc[nt], 0, 0, 0);
      }
    }
  }
}

__global__ __launch_bounds__(256, 2) void attn_k(
    float* __restrict__ Qn,                 // fp32 NHWC, updated IN-PLACE
    const u16* __restrict__ KVn, const u16* __restrict__ KVwn,
    const float* __restrict__ em) {
  __shared__ __align__(16) u16 q_t[64 * 132];   // Q window bf16 [q][d]
  __shared__ __align__(16) u16 kv_t[128 * 68];  // [key][132] or [d][68]
  __shared__ __align__(16) u16 p_t[64 * 68];    // P [q][key]

  const int wi = blockIdx.x;
  const int b = wi >> 10, wy = (wi >> 5) & 31, wx = wi & 31;
  const int Y0 = wy * 8, X0 = wx * 8;
  const int tid = threadIdx.x, lane = tid & 63, wv = tid >> 6;
  const int quad = lane >> 4, l15 = lane & 15;

  for (int i = tid; i < 2048; i += 256) {   // stage Q window fp32->bf16
    int qq = i >> 5, c4 = i & 31;
    int yy = Y0 + (qq >> 3), xx = X0 + (qq & 7);
    F4 v;
    v.v = *(const float4*)(Qn + (((b * 256 + yy) * 256 + xx) * 128 + c4 * 4));
    US4 s;
#pragma unroll
    for (int j = 0; j < 4; ++j) s.u[j] = f2b(v.f[j]);
    *(ushort4*)&q_t[qq * 132 + c4 * 4] = s.s;
  }
  float mval[4];
#pragma unroll
  for (int r = 0; r < 4; ++r) {
    int q = wv * 16 + quad * 4 + r;
    mval[r] = em[b * 65536 + (Y0 + (q >> 3)) * 256 + X0 + (q & 7)];
  }
  __syncthreads();
  bf16x8 qf[4];
#pragma unroll
  for (int kst = 0; kst < 4; ++kst)
    qf[kst] = ld8(&q_t[(wv * 16 + l15) * 132 + kst * 32 + quad * 8]);

  f32x4 o1[8], o2[8];
  float l1[4], l2[4];
  attn_branch<2>(KVn, b, Y0, X0, kv_t, p_t, qf, tid, wv, quad, l15, o1, l1);
  attn_branch<4>(KVwn, b, Y0, X0, kv_t, p_t, qf, tid, wv, quad, l15, o2, l2);

#pragma unroll
  for (int r = 0; r < 4; ++r) { l1[r] = 1.f / l1[r]; l2[r] = 1.f / l2[r]; }
#pragma unroll
  for (int nt = 0; nt < 8; ++nt) {
#pragma unroll
    for (int r = 0; r < 4; ++r) {
      int q = wv * 16 + quad * 4 + r;
      int c = nt * 16 + l15;
      int gi = ((b * 256 + Y0 + (q >> 3)) * 256 + X0 + (q & 7)) * 128 + c;
      float v = mval[r] * (o1[nt][r] * l1[r]) + (1.f - mval[r]) * (o2[nt][r] * l2[r]);
      v += Qn[gi];             // shortcut (read fp32, then overwrite in-place)
      Qn[gi] = v;
    }
  }
}

// ---------------------------------------------------------------------------
extern "C" void kernel_launch(void* const* d_in, const int* in_sizes, int n_in,
                              void* d_out, int out_size, void* d_ws, size_t ws_size,
                              hipStream_t stream) {
  (void)in_sizes; (void)n_in; (void)out_size; (void)ws_size;
  const float* xq   = (const float*)d_in[0];
  const float* xkvw = (const float*)d_in[1];
  const float* xkv  = (const float*)d_in[2];
  const float* em   = (const float*)d_in[3];
  const float* Wq   = (const float*)d_in[4];
  const float* bq   = (const float*)d_in[5];
  const float* aq   = (const float*)d_in[6];
  const float* Wkv  = (const float*)d_in[7];
  const float* bkv  = (const float*)d_in[8];
  const float* akv  = (const float*)d_in[9];
  const float* Wff  = (const float*)d_in[10];
  const float* bff  = (const float*)d_in[11];
  const float* aff  = (const float*)d_in[12];

  char* ws = (char*)d_ws;
  float* Qn = (float*)ws;                       // 67,108,864 B
  u16* KVn  = (u16*)(ws + 67108864);            // 67,108,864 B
  u16* KVwn = (u16*)(ws + 134217728);           // 134,217,728 B
  u16* wtq  = (u16*)d_out;                      // dead region until final conv
  u16* wtkv = (u16*)d_out + 147456;
  u16* wtff = KVwn;                             // KVwn dead after attn

  prep_w<<<576, 256, 0, stream>>>(Wq, wtq);
  prep_w<<<576, 256, 0, stream>>>(Wkv, wtkv);

  conv3x3_k<<<2048, 256, 0, stream>>>(xq,   wtq,  bq,  aq,  Qn,   0, 1);
  conv3x3_k<<<4096, 256, 0, stream>>>(xkv,  wtkv, bkv, akv, KVn,  0, 2);
  conv3x3_k<<<8192, 256, 0, stream>>>(xkvw, wtkv, bkv, akv, KVwn, 0, 2);

  attn_k<<<2048, 256, 0, stream>>>(Qn, KVn, KVwn, em);

  prep_w<<<576, 256, 0, stream>>>(Wff, wtff);
  conv3x3_k<<<2048, 256, 0, stream>>>(Qn, wtff, bff, aff, d_out, 1, 0);
}